// Round 5
// baseline (11473.663 us; speedup 1.0000x reference)
//
#include <hip/hip_runtime.h>
#include <math.h>

// Problem constants (match setup_inputs in the reference).
#define B_SZ   32
#define T_SZ   400
#define D_SZ   2048
#define S_DEN  2000
#define E_DEN  60000
#define S_NUM  512
#define E_NUM  2048
#define DEN_C  1e-5f
#define NUM_C  1e-20f

#define NTHR   1024
#define EPT    59            // edges per thread: 59*1024 = 60416 >= 60000

// Workspace layout (bytes, 64-aligned chunks).
#define REC_OFF     0u          // int4[E_DEN] CSR {in, pdf, prob, out} sorted by out
#define PACK_OFF    960000u     // uint2[E_DEN] packed {in|pdf<<11|drow<<22, prob}
#define ROWPTR_OFF  1440000u    // int[S_DEN+1]
#define CNT_OFF     1448064u    // int[S_DEN]
#define CUR_OFF     1456064u    // int[S_DEN]
#define SROW_OFF    1464064u    // int[1024] per-thread start row
#define LF_OFF      1468160u    // float: sum(den_leaky*den_final)
#define TOTD_OFF    1468224u    // float[32]
#define TOTN_OFF    1468352u    // float[32]
#define WS_BYTES    1468480u

// ---------------- prep kernels ----------------
__global__ void prep_init(const float* __restrict__ den_leaky,
                          const float* __restrict__ den_final, char* ws) {
    int* cnt = (int*)(ws + CNT_OFF);
    int* cur = (int*)(ws + CUR_OFF);
    __shared__ float part[256];
    int tid = threadIdx.x;
    float s = 0.f;
    for (int i = tid; i < S_DEN; i += 256) {
        cnt[i] = 0; cur[i] = 0;
        s += den_leaky[i] * den_final[i];
    }
    part[tid] = s;
    __syncthreads();
    for (int o = 128; o > 0; o >>= 1) { if (tid < o) part[tid] += part[tid + o]; __syncthreads(); }
    if (tid == 0) *(float*)(ws + LF_OFF) = part[0];
}

__global__ void prep_hist(const int* __restrict__ e_out, char* ws) {
    int e = blockIdx.x * blockDim.x + threadIdx.x;
    if (e < E_DEN) atomicAdd((int*)(ws + CNT_OFF) + e_out[e], 1);
}

__global__ __launch_bounds__(1024) void prep_scan(char* ws) {
    __shared__ int sb[2][2048];
    const int* cnt = (const int*)(ws + CNT_OFF);
    int* rowp = (int*)(ws + ROWPTR_OFF);
    int tid = threadIdx.x;
    for (int i = tid; i < 2048; i += 1024) sb[0][i] = (i < S_DEN) ? cnt[i] : 0;
    __syncthreads();
    int cur = 0;
    for (int d = 1; d < 2048; d <<= 1) {
        for (int i = tid; i < 2048; i += 1024)
            sb[1 - cur][i] = sb[cur][i] + ((i >= d) ? sb[cur][i - d] : 0);
        __syncthreads();
        cur ^= 1;
    }
    if (tid == 0) rowp[0] = 0;
    for (int i = tid; i < S_DEN; i += 1024) rowp[i + 1] = sb[cur][i];
}

__global__ void prep_scatter(const int* __restrict__ e_in, const int* __restrict__ e_out,
                             const int* __restrict__ e_pdf, const float* __restrict__ e_prob,
                             char* ws) {
    int e = blockIdx.x * blockDim.x + threadIdx.x;
    if (e >= E_DEN) return;
    const int* rowp = (const int*)(ws + ROWPTR_OFF);
    int* cur = (int*)(ws + CUR_OFF);
    int4* recs = (int4*)(ws + REC_OFF);
    int o = e_out[e];
    int pos = rowp[o] + atomicAdd(&cur[o], 1);
    int4 r;
    r.x = e_in[e]; r.y = e_pdf[e];
    r.z = __float_as_int(e_prob[e]);
    r.w = o;
    recs[pos] = r;
}

// Pack to 8B records with row-advance deltas + per-thread start rows.
__global__ void prep_pack(char* ws) {
    int k = blockIdx.x * blockDim.x + threadIdx.x;
    if (k >= E_DEN) return;
    const int4* r4 = (const int4*)(ws + REC_OFF);
    uint2* pk = (uint2*)(ws + PACK_OFF);
    int4 r = r4[k];
    int out = r.w;
    int nxt = (k + 1 < E_DEN) ? r4[k + 1].w : out;   // last edge: delta 0
    unsigned d = (unsigned)(nxt - out);
    if (d > 1023u) d = 1023u;                        // unreachable with this graph
    pk[k] = make_uint2((unsigned)r.x | ((unsigned)r.y << 11) | (d << 22),
                       (unsigned)r.z);
    if ((k % EPT) == 0) ((int*)(ws + SROW_OFF))[k / EPT] = out;
}

// ---------------- main kernel: 32 den blocks + 32 num blocks, no grid sync ----
__global__ __launch_bounds__(NTHR) void chain_fwd2(
    const float* __restrict__ x, const int* __restrict__ lengths,
    const float* __restrict__ den_leaky, const float* __restrict__ den_final,
    const int* __restrict__ num_in, const int* __restrict__ num_out,
    const int* __restrict__ num_pdf, const float* __restrict__ num_prob,
    const float* __restrict__ num_leaky, const float* __restrict__ num_final,
    char* __restrict__ ws)
{
    __shared__ float alpha[2048];
    __shared__ float xrow[2048];
    __shared__ float anew[2048];
    __shared__ float red[34];
    const int tid = threadIdx.x;

    if (blockIdx.x < B_SZ) {
        // =============== den: one block per utterance, fully LDS-resident ========
        const int b = blockIdx.x;
        const uint2* __restrict__ recs = (const uint2*)(ws + PACK_OFF);
        const int*   __restrict__ srow = (const int*)(ws + SROW_OFF);
        float* __restrict__ totd = (float*)(ws + TOTD_OFF);
        const float LF = *(const float*)(ws + LF_OFF);
        const int len = lengths[b];
        const float* xb = x + (size_t)b * T_SZ * D_SZ;

        // adash0 = alpha0 (asum=1): mass on state 0 + leaky.
        alpha[tid]        = ((tid < S_DEN) ? DEN_C * den_leaky[tid] : 0.f) + (tid == 0 ? 1.f : 0.f);
        alpha[tid + 1024] = (tid + 1024 < S_DEN) ? DEN_C * den_leaky[tid + 1024] : 0.f;

        const int k0 = min(tid * EPT, E_DEN);
        const int k1 = min(k0 + EPT, E_DEN);
        const int row0 = srow[tid];   // garbage for empty ranges; unused then
        float logz = 0.f;
        float tot = 0.f;
        __syncthreads();

        for (int t = 0; t < len; ++t) {
            // Phase A: stage exp(clip(x[b,t,:])), zero anew.
            const float* xp = xb + (size_t)t * D_SZ;
            xrow[tid]        = __expf(fminf(fmaxf(xp[tid],        -30.f), 30.f));
            xrow[tid + 1024] = __expf(fminf(fmaxf(xp[tid + 1024], -30.f), 30.f));
            anew[tid] = 0.f; anew[tid + 1024] = 0.f;
            __syncthreads();

            // Phase B: per-thread contiguous CSR range, register accumulation,
            // flush on row-end flag (rare LDS atomic).
            float acc = 0.f;
            int row = row0;
            #pragma unroll 4
            for (int k = k0; k < k1; ++k) {
                uint2 r = recs[k];
                float a  = alpha[r.x & 2047u];
                float xv = xrow[(r.x >> 11) & 2047u];
                acc = __fmaf_rn(a * __uint_as_float(r.y), xv, acc);
                unsigned d = r.x >> 22;
                if (d) { atomicAdd(&anew[row], acc); acc = 0.f; row += d; }
            }
            if (acc != 0.f) atomicAdd(&anew[row], acc);
            __syncthreads();

            // Phase C: asum (+ pfin on the final frame).
            const bool last = (t == len - 1);
            float ps = anew[tid] + anew[tid + 1024];
            float pf = 0.f;
            if (last) {
                float f0 = (tid < S_DEN) ? den_final[tid] : 0.f;
                float f1 = (tid + 1024 < S_DEN) ? den_final[tid + 1024] : 0.f;
                pf = anew[tid] * f0 + anew[tid + 1024] * f1;
            }
            #pragma unroll
            for (int o = 32; o > 0; o >>= 1) {
                ps += __shfl_down(ps, o, 64);
                pf += __shfl_down(pf, o, 64);
            }
            if ((tid & 63) == 0) { red[tid >> 6] = ps; red[16 + (tid >> 6)] = pf; }
            __syncthreads();
            if (tid < 64) {
                float v = (tid < 16) ? red[tid] : 0.f;
                float w = (tid < 16) ? red[16 + tid] : 0.f;
                #pragma unroll
                for (int o = 8; o > 0; o >>= 1) {
                    v += __shfl_down(v, o, 64);
                    w += __shfl_down(w, o, 64);
                }
                if (tid == 0) { red[32] = v; red[33] = w; }
            }
            __syncthreads();
            const float asum = red[32];
            const float inv  = 1.f / asum;

            // Phase D: alpha <- adash (renorm + leaky folded).
            {
                float l0 = (tid < S_DEN) ? den_leaky[tid] : 0.f;
                float l1 = (tid + 1024 < S_DEN) ? den_leaky[tid + 1024] : 0.f;
                alpha[tid]        = __fmaf_rn(anew[tid],        inv, DEN_C * l0);
                alpha[tid + 1024] = __fmaf_rn(anew[tid + 1024], inv, DEN_C * l1);
            }
            if (last && tid == 0)
                tot = logz + logf(asum) + logf(__fmaf_rn(red[33], inv, DEN_C * LF));
            logz += logf(asum);
            __syncthreads();
        }
        if (tid == 0) totd[b] = tot;
    } else {
        // =============== num: one block per utterance, LDS-local =================
        const int b = blockIdx.x - B_SZ;
        float* nalpha = alpha;             // [512]
        float* nanew  = anew;              // [512]
        float* totn   = (float*)(ws + TOTN_OFF);

        const int len = lengths[b];
        const float lk = (tid < S_NUM) ? num_leaky[b * S_NUM + tid] : 0.f;
        const float fn = (tid < S_NUM) ? num_final[b * S_NUM + tid] : 0.f;
        const int*   ein  = num_in   + b * E_NUM;
        const int*   eout = num_out  + b * E_NUM;
        const int*   epdf = num_pdf  + b * E_NUM;
        const float* eprb = num_prob + b * E_NUM;
        const float* xb = x + (size_t)b * T_SZ * D_SZ;

        if (tid < S_NUM) nalpha[tid] = NUM_C * lk + (tid == 0 ? 1.f : 0.f);
        float logz = 0.f;
        __syncthreads();

        for (int t = 0; t < len; ++t) {
            if (tid < S_NUM) nanew[tid] = 0.f;
            const float* xp = xb + (size_t)t * D_SZ;
            xrow[tid]        = __expf(fminf(fmaxf(xp[tid],        -30.f), 30.f));
            xrow[tid + 1024] = __expf(fminf(fmaxf(xp[tid + 1024], -30.f), 30.f));
            __syncthreads();
            for (int e = tid; e < E_NUM; e += NTHR) {
                float v = nalpha[ein[e]] * eprb[e] * xrow[epdf[e]];
                atomicAdd(&nanew[eout[e]], v);
            }
            __syncthreads();
            float ps = (tid < S_NUM) ? nanew[tid] : 0.f;
            #pragma unroll
            for (int o = 32; o > 0; o >>= 1) ps += __shfl_down(ps, o, 64);
            if ((tid & 63) == 0) red[tid >> 6] = ps;
            __syncthreads();
            if (tid < 64) {
                float v2 = (tid < 16) ? red[tid] : 0.f;
                #pragma unroll
                for (int o = 8; o > 0; o >>= 1) v2 += __shfl_down(v2, o, 64);
                if (tid == 0) red[32] = v2;
            }
            __syncthreads();
            const float asum = red[32];
            if (tid < S_NUM)
                nalpha[tid] = __fmaf_rn(NUM_C * lk, asum, nanew[tid]) * (1.f / asum);
            logz += logf(asum);
            __syncthreads();
        }
        float fs = (tid < S_NUM) ? nalpha[tid] * fn : 0.f;
        #pragma unroll
        for (int o = 32; o > 0; o >>= 1) fs += __shfl_down(fs, o, 64);
        if ((tid & 63) == 0) red[tid >> 6] = fs;
        __syncthreads();
        if (tid < 64) {
            float v2 = (tid < 16) ? red[tid] : 0.f;
            #pragma unroll
            for (int o = 8; o > 0; o >>= 1) v2 += __shfl_down(v2, o, 64);
            if (tid == 0) totn[b] = logz + logf(v2);
        }
    }
}

__global__ void combine2(const char* __restrict__ ws, const int* __restrict__ lengths,
                         float* __restrict__ out) {
    const float* totd = (const float*)(ws + TOTD_OFF);
    const float* totn = (const float*)(ws + TOTN_OFF);
    int tid = threadIdx.x;
    float v = 0.f, l = 0.f;
    if (tid < B_SZ) { v = totd[tid] - totn[tid]; l = (float)lengths[tid]; }
    #pragma unroll
    for (int o = 32; o > 0; o >>= 1) { v += __shfl_down(v, o, 64); l += __shfl_down(l, o, 64); }
    if (tid == 0) out[0] = v / l;
}

// ===================== round-1 fallback (used only if ws too small) ==========
__global__ __launch_bounds__(1024) void chain_fwd_kernel(
    const float* __restrict__ x, const int* __restrict__ lengths,
    const int* __restrict__ den_in, const int* __restrict__ den_out,
    const int* __restrict__ den_pdf, const float* __restrict__ den_prob,
    const float* __restrict__ den_leaky, const float* __restrict__ den_final,
    const int* __restrict__ num_in, const int* __restrict__ num_out,
    const int* __restrict__ num_pdf, const float* __restrict__ num_prob,
    const float* __restrict__ num_leaky, const float* __restrict__ num_final,
    float* __restrict__ part)
{
    __shared__ float xrow[D_SZ];
    __shared__ float alpha[S_DEN];
    __shared__ float anew[S_DEN];
    __shared__ float red[17];
    const int tid = threadIdx.x;
    const int nthr = 1024;
    const bool is_den = blockIdx.x < B_SZ;
    const int b = blockIdx.x & (B_SZ - 1);
    int S, E;
    const int *e_in, *e_out, *e_pdf;
    const float *e_prob, *leaky, *fin;
    float coeff;
    if (is_den) {
        S = S_DEN; E = E_DEN;
        e_in = den_in; e_out = den_out; e_pdf = den_pdf; e_prob = den_prob;
        leaky = den_leaky; fin = den_final; coeff = DEN_C;
    } else {
        S = S_NUM; E = E_NUM;
        e_in = num_in + b * E_NUM; e_out = num_out + b * E_NUM;
        e_pdf = num_pdf + b * E_NUM; e_prob = num_prob + b * E_NUM;
        leaky = num_leaky + b * S_NUM; fin = num_final + b * S_NUM;
        coeff = NUM_C;
    }
    const int len = lengths[b];
    const float* xb = x + (size_t)b * T_SZ * D_SZ;
    for (int s = tid; s < S; s += nthr)
        alpha[s] = coeff * leaky[s] + (s == 0 ? 1.0f : 0.0f);
    float logz = 0.0f;
    for (int t = 0; t < len; ++t) {
        for (int s = tid; s < S; s += nthr) anew[s] = 0.0f;
        const float* xt = xb + (size_t)t * D_SZ;
        for (int d = tid; d < D_SZ; d += nthr)
            xrow[d] = __expf(fminf(fmaxf(xt[d], -30.0f), 30.0f));
        __syncthreads();
        for (int e = tid; e < E; e += nthr) {
            float v = alpha[e_in[e]] * e_prob[e] * xrow[e_pdf[e]];
            atomicAdd(&anew[e_out[e]], v);
        }
        __syncthreads();
        float ps = 0.0f;
        for (int s = tid; s < S; s += nthr) ps += anew[s];
        #pragma unroll
        for (int off = 32; off > 0; off >>= 1) ps += __shfl_down(ps, off, 64);
        if ((tid & 63) == 0) red[tid >> 6] = ps;
        __syncthreads();
        if (tid < 64) {
            float v = (tid < 16) ? red[tid] : 0.0f;
            #pragma unroll
            for (int off = 8; off > 0; off >>= 1) v += __shfl_down(v, off, 64);
            if (tid == 0) red[16] = v;
        }
        __syncthreads();
        const float asum = red[16];
        const float inv = 1.0f / asum;
        for (int s = tid; s < S; s += nthr)
            alpha[s] = (anew[s] + coeff * leaky[s] * asum) * inv;
        logz += logf(asum);
        __syncthreads();
    }
    float fs = 0.0f;
    for (int s = tid; s < S; s += nthr) fs += alpha[s] * fin[s];
    #pragma unroll
    for (int off = 32; off > 0; off >>= 1) fs += __shfl_down(fs, off, 64);
    if ((tid & 63) == 0) red[tid >> 6] = fs;
    __syncthreads();
    if (tid < 64) {
        float v = (tid < 16) ? red[tid] : 0.0f;
        #pragma unroll
        for (int off = 8; off > 0; off >>= 1) v += __shfl_down(v, off, 64);
        if (tid == 0) part[blockIdx.x] = logz + logf(v);
    }
}

__global__ void combine_kernel(const float* __restrict__ part,
                               const int* __restrict__ lengths,
                               float* __restrict__ out)
{
    int tid = threadIdx.x;
    float v = 0.0f, l = 0.0f;
    if (tid < B_SZ) { v = part[tid] - part[B_SZ + tid]; l = (float)lengths[tid]; }
    #pragma unroll
    for (int off = 32; off > 0; off >>= 1) { v += __shfl_down(v, off, 64); l += __shfl_down(l, off, 64); }
    if (tid == 0) out[0] = v / l;
}

// ---------------------------------------------------------------------------
extern "C" void kernel_launch(void* const* d_in, const int* in_sizes, int n_in,
                              void* d_out, int out_size, void* d_ws, size_t ws_size,
                              hipStream_t stream)
{
    const float* x          = (const float*)d_in[0];
    const int*   lengths    = (const int*)  d_in[1];
    const int*   den_in_p   = (const int*)  d_in[2];
    const int*   den_out_p  = (const int*)  d_in[3];
    const int*   den_pdf_p  = (const int*)  d_in[4];
    const float* den_prob_p = (const float*)d_in[5];
    const float* den_leaky  = (const float*)d_in[6];
    const float* den_final  = (const float*)d_in[7];
    const int*   num_in_p   = (const int*)  d_in[8];
    const int*   num_out_p  = (const int*)  d_in[9];
    const int*   num_pdf_p  = (const int*)  d_in[10];
    const float* num_prob_p = (const float*)d_in[11];
    const float* num_leaky  = (const float*)d_in[12];
    const float* num_final  = (const float*)d_in[13];

    if (ws_size >= WS_BYTES) {
        char* ws = (char*)d_ws;
        hipLaunchKernelGGL(prep_init, dim3(1), dim3(256), 0, stream,
                           den_leaky, den_final, ws);
        hipLaunchKernelGGL(prep_hist, dim3((E_DEN + 255) / 256), dim3(256), 0, stream,
                           den_out_p, ws);
        hipLaunchKernelGGL(prep_scan, dim3(1), dim3(1024), 0, stream, ws);
        hipLaunchKernelGGL(prep_scatter, dim3((E_DEN + 255) / 256), dim3(256), 0, stream,
                           den_in_p, den_out_p, den_pdf_p, den_prob_p, ws);
        hipLaunchKernelGGL(prep_pack, dim3((E_DEN + 255) / 256), dim3(256), 0, stream, ws);
        hipLaunchKernelGGL(chain_fwd2, dim3(2 * B_SZ), dim3(NTHR), 0, stream,
                           x, lengths, den_leaky, den_final,
                           num_in_p, num_out_p, num_pdf_p, num_prob_p,
                           num_leaky, num_final, ws);
        hipLaunchKernelGGL(combine2, dim3(1), dim3(64), 0, stream,
                           ws, lengths, (float*)d_out);
    } else {
        float* part = (float*)d_ws;
        hipLaunchKernelGGL(chain_fwd_kernel, dim3(2 * B_SZ), dim3(1024), 0, stream,
                           x, lengths,
                           den_in_p, den_out_p, den_pdf_p, den_prob_p, den_leaky, den_final,
                           num_in_p, num_out_p, num_pdf_p, num_prob_p, num_leaky, num_final,
                           part);
        hipLaunchKernelGGL(combine_kernel, dim3(1), dim3(64), 0, stream,
                           part, lengths, (float*)d_out);
    }
}

// Round 6
// 6577.374 us; speedup vs baseline: 1.7444x; 1.7444x over previous
//
#include <hip/hip_runtime.h>
#include <math.h>

// Problem constants (match setup_inputs in the reference).
#define B_SZ   32
#define T_SZ   400
#define D_SZ   2048
#define S_DEN  2000
#define E_DEN  60000
#define S_NUM  512
#define E_NUM  2048
#define DEN_C  1e-5f
#define NUM_C  1e-20f

#define NTHR   1024
#define EPT    64            // edges per thread (padded): 64*1024 = 65536
#define EPAD   65536

// Workspace layout (bytes, 64-aligned chunks).
#define REC_OFF     0u          // int4[E_DEN] CSR {in, pdf, prob, out} sorted by out
#define PACK_OFF    960000u     // uint2[EPAD] packed {in|pdf<<11|drow<<22, prob}
#define ROWPTR_OFF  1484288u    // int[S_DEN+1]
#define CNT_OFF     1492352u    // int[S_DEN]
#define CUR_OFF     1500352u    // int[S_DEN]
#define SROW_OFF    1508352u    // int[1024] per-thread start row
#define LF_OFF      1512448u    // float: sum(den_leaky*den_final)
#define TOTD_OFF    1512512u    // float[32]
#define TOTN_OFF    1512640u    // float[32]
#define WS_BYTES    1512768u

// ---------------- prep kernels ----------------
__global__ void prep_init(const float* __restrict__ den_leaky,
                          const float* __restrict__ den_final, char* ws) {
    int* cnt = (int*)(ws + CNT_OFF);
    int* cur = (int*)(ws + CUR_OFF);
    int* srow = (int*)(ws + SROW_OFF);
    __shared__ float part[256];
    int tid = threadIdx.x;
    float s = 0.f;
    for (int i = tid; i < S_DEN; i += 256) {
        cnt[i] = 0; cur[i] = 0;
        s += den_leaky[i] * den_final[i];
    }
    for (int i = tid; i < 1024; i += 256) srow[i] = 0;
    part[tid] = s;
    __syncthreads();
    for (int o = 128; o > 0; o >>= 1) { if (tid < o) part[tid] += part[tid + o]; __syncthreads(); }
    if (tid == 0) *(float*)(ws + LF_OFF) = part[0];
}

__global__ void prep_hist(const int* __restrict__ e_out, char* ws) {
    int e = blockIdx.x * blockDim.x + threadIdx.x;
    if (e < E_DEN) atomicAdd((int*)(ws + CNT_OFF) + e_out[e], 1);
}

__global__ __launch_bounds__(1024) void prep_scan(char* ws) {
    __shared__ int sb[2][2048];
    const int* cnt = (const int*)(ws + CNT_OFF);
    int* rowp = (int*)(ws + ROWPTR_OFF);
    int tid = threadIdx.x;
    for (int i = tid; i < 2048; i += 1024) sb[0][i] = (i < S_DEN) ? cnt[i] : 0;
    __syncthreads();
    int cur = 0;
    for (int d = 1; d < 2048; d <<= 1) {
        for (int i = tid; i < 2048; i += 1024)
            sb[1 - cur][i] = sb[cur][i] + ((i >= d) ? sb[cur][i - d] : 0);
        __syncthreads();
        cur ^= 1;
    }
    if (tid == 0) rowp[0] = 0;
    for (int i = tid; i < S_DEN; i += 1024) rowp[i + 1] = sb[cur][i];
}

__global__ void prep_scatter(const int* __restrict__ e_in, const int* __restrict__ e_out,
                             const int* __restrict__ e_pdf, const float* __restrict__ e_prob,
                             char* ws) {
    int e = blockIdx.x * blockDim.x + threadIdx.x;
    if (e >= E_DEN) return;
    const int* rowp = (const int*)(ws + ROWPTR_OFF);
    int* cur = (int*)(ws + CUR_OFF);
    int4* recs = (int4*)(ws + REC_OFF);
    int o = e_out[e];
    int pos = rowp[o] + atomicAdd(&cur[o], 1);
    int4 r;
    r.x = e_in[e]; r.y = e_pdf[e];
    r.z = __float_as_int(e_prob[e]);
    r.w = o;
    recs[pos] = r;
}

// Pack to 8B records with row-advance deltas + per-thread start rows.
// Pads to EPAD with dummy records (prob=0, delta=0) so the main loop has a
// fixed trip count (ws is re-poisoned each launch, so dummies must be written).
__global__ void prep_pack(char* ws) {
    int k = blockIdx.x * blockDim.x + threadIdx.x;
    if (k >= EPAD) return;
    uint2* pk = (uint2*)(ws + PACK_OFF);
    if (k >= E_DEN) { pk[k] = make_uint2(0u, 0u); return; }
    const int4* r4 = (const int4*)(ws + REC_OFF);
    int4 r = r4[k];
    int out = r.w;
    int nxt = (k + 1 < E_DEN) ? r4[k + 1].w : out;   // last edge: delta 0
    unsigned d = (unsigned)(nxt - out);
    if (d > 1023u) d = 1023u;                        // unreachable with this graph
    pk[k] = make_uint2((unsigned)r.x | ((unsigned)r.y << 11) | (d << 22),
                       (unsigned)r.z);
    if ((k & (EPT - 1)) == 0) ((int*)(ws + SROW_OFF))[k / EPT] = out;
}

// ---------------- main kernel: 32 den blocks + 32 num blocks, no grid sync ----
__global__ __launch_bounds__(NTHR, 4) void chain_fwd2(
    const float* __restrict__ x, const int* __restrict__ lengths,
    const float* __restrict__ den_leaky, const float* __restrict__ den_final,
    const int* __restrict__ num_in, const int* __restrict__ num_out,
    const int* __restrict__ num_pdf, const float* __restrict__ num_prob,
    const float* __restrict__ num_leaky, const float* __restrict__ num_final,
    char* __restrict__ ws)
{
    __shared__ float alpha[2048];
    __shared__ float xrow[2048];
    __shared__ float anew[2048];
    __shared__ float red[34];
    const int tid = threadIdx.x;

    if (blockIdx.x < B_SZ) {
        // =============== den: one block per utterance, fully LDS-resident ========
        const int b = blockIdx.x;
        const uint4* __restrict__ pk4 = (const uint4*)(ws + PACK_OFF); // 2 recs/uint4
        const int*   __restrict__ srow = (const int*)(ws + SROW_OFF);
        float* __restrict__ totd = (float*)(ws + TOTD_OFF);
        const float LF = *(const float*)(ws + LF_OFF);
        const int len = lengths[b];
        const float* xb = x + (size_t)b * T_SZ * D_SZ;

        // adash0 = alpha0 (asum=1): mass on state 0 + leaky.
        alpha[tid]        = ((tid < S_DEN) ? DEN_C * den_leaky[tid] : 0.f) + (tid == 0 ? 1.f : 0.f);
        alpha[tid + 1024] = (tid + 1024 < S_DEN) ? DEN_C * den_leaky[tid + 1024] : 0.f;

        const int qb = tid * (EPT / 2);   // uint4 index base: 64 recs = 32 uint4
        const int row0 = srow[tid];
        float logz = 0.f;
        float tot = 0.f;
        __syncthreads();

        for (int t = 0; t < len; ++t) {
            // Phase A: stage exp(clip(x[b,t,:])), zero anew.
            const float* xp = xb + (size_t)t * D_SZ;
            xrow[tid]        = __expf(fminf(fmaxf(xp[tid],        -30.f), 30.f));
            xrow[tid + 1024] = __expf(fminf(fmaxf(xp[tid + 1024], -30.f), 30.f));
            anew[tid] = 0.f; anew[tid + 1024] = 0.f;
            __syncthreads();

            // Phase B: 8 batches x 8 edges. Records double-buffered in registers
            // (prefetch one batch ahead); all 16 LDS gathers of a batch issue
            // before the FMA/flush chain consumes them.
            float acc = 0.f;
            int row = row0;
            uint4 c0 = pk4[qb + 0], c1 = pk4[qb + 1], c2 = pk4[qb + 2], c3 = pk4[qb + 3];
            #pragma unroll
            for (int bt = 0; bt < 8; ++bt) {
                uint4 n0 = c0, n1 = c1, n2 = c2, n3 = c3;
                if (bt < 7) {
                    const int nq = qb + (bt + 1) * 4;
                    n0 = pk4[nq]; n1 = pk4[nq + 1]; n2 = pk4[nq + 2]; n3 = pk4[nq + 3];
                }
                const unsigned w[8] = {c0.x, c0.z, c1.x, c1.z, c2.x, c2.z, c3.x, c3.z};
                const unsigned p[8] = {c0.y, c0.w, c1.y, c1.w, c2.y, c2.w, c3.y, c3.w};
                float av[8], xv[8];
                #pragma unroll
                for (int i = 0; i < 8; ++i) av[i] = alpha[w[i] & 2047u];
                #pragma unroll
                for (int i = 0; i < 8; ++i) xv[i] = xrow[(w[i] >> 11) & 2047u];
                #pragma unroll
                for (int i = 0; i < 8; ++i) {
                    acc = __fmaf_rn(av[i] * __uint_as_float(p[i]), xv[i], acc);
                    const unsigned d = w[i] >> 22;
                    if (d) { atomicAdd(&anew[row], acc); acc = 0.f; row += (int)d; }
                }
                c0 = n0; c1 = n1; c2 = n2; c3 = n3;
            }
            if (acc != 0.f) atomicAdd(&anew[row], acc);
            __syncthreads();

            // Phase C: asum (+ pfin on the final frame).
            const bool last = (t == len - 1);
            float ps = anew[tid] + anew[tid + 1024];
            float pf = 0.f;
            if (last) {
                float f0 = (tid < S_DEN) ? den_final[tid] : 0.f;
                float f1 = (tid + 1024 < S_DEN) ? den_final[tid + 1024] : 0.f;
                pf = anew[tid] * f0 + anew[tid + 1024] * f1;
            }
            #pragma unroll
            for (int o = 32; o > 0; o >>= 1) {
                ps += __shfl_down(ps, o, 64);
                pf += __shfl_down(pf, o, 64);
            }
            if ((tid & 63) == 0) { red[tid >> 6] = ps; red[16 + (tid >> 6)] = pf; }
            __syncthreads();
            if (tid < 64) {
                float v = (tid < 16) ? red[tid] : 0.f;
                float w2 = (tid < 16) ? red[16 + tid] : 0.f;
                #pragma unroll
                for (int o = 8; o > 0; o >>= 1) {
                    v += __shfl_down(v, o, 64);
                    w2 += __shfl_down(w2, o, 64);
                }
                if (tid == 0) { red[32] = v; red[33] = w2; }
            }
            __syncthreads();
            const float asum = red[32];
            const float inv  = 1.f / asum;

            // Phase D: alpha <- adash (renorm + leaky folded).
            {
                float l0 = (tid < S_DEN) ? den_leaky[tid] : 0.f;
                float l1 = (tid + 1024 < S_DEN) ? den_leaky[tid + 1024] : 0.f;
                alpha[tid]        = __fmaf_rn(anew[tid],        inv, DEN_C * l0);
                alpha[tid + 1024] = __fmaf_rn(anew[tid + 1024], inv, DEN_C * l1);
            }
            if (last && tid == 0)
                tot = logz + logf(asum) + logf(__fmaf_rn(red[33], inv, DEN_C * LF));
            logz += logf(asum);
            __syncthreads();
        }
        if (tid == 0) totd[b] = tot;
    } else {
        // =============== num: one block per utterance, LDS-local =================
        const int b = blockIdx.x - B_SZ;
        float* nalpha = alpha;             // [512]
        float* nanew  = anew;              // [512]
        float* totn   = (float*)(ws + TOTN_OFF);

        const int len = lengths[b];
        const float lk = (tid < S_NUM) ? num_leaky[b * S_NUM + tid] : 0.f;
        const float fn = (tid < S_NUM) ? num_final[b * S_NUM + tid] : 0.f;
        const int*   ein  = num_in   + b * E_NUM;
        const int*   eout = num_out  + b * E_NUM;
        const int*   epdf = num_pdf  + b * E_NUM;
        const float* eprb = num_prob + b * E_NUM;
        const float* xb = x + (size_t)b * T_SZ * D_SZ;

        if (tid < S_NUM) nalpha[tid] = NUM_C * lk + (tid == 0 ? 1.f : 0.f);
        float logz = 0.f;
        __syncthreads();

        for (int t = 0; t < len; ++t) {
            if (tid < S_NUM) nanew[tid] = 0.f;
            const float* xp = xb + (size_t)t * D_SZ;
            xrow[tid]        = __expf(fminf(fmaxf(xp[tid],        -30.f), 30.f));
            xrow[tid + 1024] = __expf(fminf(fmaxf(xp[tid + 1024], -30.f), 30.f));
            __syncthreads();
            for (int e = tid; e < E_NUM; e += NTHR) {
                float v = nalpha[ein[e]] * eprb[e] * xrow[epdf[e]];
                atomicAdd(&nanew[eout[e]], v);
            }
            __syncthreads();
            float ps = (tid < S_NUM) ? nanew[tid] : 0.f;
            #pragma unroll
            for (int o = 32; o > 0; o >>= 1) ps += __shfl_down(ps, o, 64);
            if ((tid & 63) == 0) red[tid >> 6] = ps;
            __syncthreads();
            if (tid < 64) {
                float v2 = (tid < 16) ? red[tid] : 0.f;
                #pragma unroll
                for (int o = 8; o > 0; o >>= 1) v2 += __shfl_down(v2, o, 64);
                if (tid == 0) red[32] = v2;
            }
            __syncthreads();
            const float asum = red[32];
            if (tid < S_NUM)
                nalpha[tid] = __fmaf_rn(NUM_C * lk, asum, nanew[tid]) * (1.f / asum);
            logz += logf(asum);
            __syncthreads();
        }
        float fs = (tid < S_NUM) ? nalpha[tid] * fn : 0.f;
        #pragma unroll
        for (int o = 32; o > 0; o >>= 1) fs += __shfl_down(fs, o, 64);
        if ((tid & 63) == 0) red[tid >> 6] = fs;
        __syncthreads();
        if (tid < 64) {
            float v2 = (tid < 16) ? red[tid] : 0.f;
            #pragma unroll
            for (int o = 8; o > 0; o >>= 1) v2 += __shfl_down(v2, o, 64);
            if (tid == 0) totn[b] = logz + logf(v2);
        }
    }
}

__global__ void combine2(const char* __restrict__ ws, const int* __restrict__ lengths,
                         float* __restrict__ out) {
    const float* totd = (const float*)(ws + TOTD_OFF);
    const float* totn = (const float*)(ws + TOTN_OFF);
    int tid = threadIdx.x;
    float v = 0.f, l = 0.f;
    if (tid < B_SZ) { v = totd[tid] - totn[tid]; l = (float)lengths[tid]; }
    #pragma unroll
    for (int o = 32; o > 0; o >>= 1) { v += __shfl_down(v, o, 64); l += __shfl_down(l, o, 64); }
    if (tid == 0) out[0] = v / l;
}

// ===================== round-1 fallback (used only if ws too small) ==========
__global__ __launch_bounds__(1024) void chain_fwd_kernel(
    const float* __restrict__ x, const int* __restrict__ lengths,
    const int* __restrict__ den_in, const int* __restrict__ den_out,
    const int* __restrict__ den_pdf, const float* __restrict__ den_prob,
    const float* __restrict__ den_leaky, const float* __restrict__ den_final,
    const int* __restrict__ num_in, const int* __restrict__ num_out,
    const int* __restrict__ num_pdf, const float* __restrict__ num_prob,
    const float* __restrict__ num_leaky, const float* __restrict__ num_final,
    float* __restrict__ part)
{
    __shared__ float xrow[D_SZ];
    __shared__ float alpha[S_DEN];
    __shared__ float anew[S_DEN];
    __shared__ float red[17];
    const int tid = threadIdx.x;
    const int nthr = 1024;
    const bool is_den = blockIdx.x < B_SZ;
    const int b = blockIdx.x & (B_SZ - 1);
    int S, E;
    const int *e_in, *e_out, *e_pdf;
    const float *e_prob, *leaky, *fin;
    float coeff;
    if (is_den) {
        S = S_DEN; E = E_DEN;
        e_in = den_in; e_out = den_out; e_pdf = den_pdf; e_prob = den_prob;
        leaky = den_leaky; fin = den_final; coeff = DEN_C;
    } else {
        S = S_NUM; E = E_NUM;
        e_in = num_in + b * E_NUM; e_out = num_out + b * E_NUM;
        e_pdf = num_pdf + b * E_NUM; e_prob = num_prob + b * E_NUM;
        leaky = num_leaky + b * S_NUM; fin = num_final + b * S_NUM;
        coeff = NUM_C;
    }
    const int len = lengths[b];
    const float* xb = x + (size_t)b * T_SZ * D_SZ;
    for (int s = tid; s < S; s += nthr)
        alpha[s] = coeff * leaky[s] + (s == 0 ? 1.0f : 0.0f);
    float logz = 0.0f;
    for (int t = 0; t < len; ++t) {
        for (int s = tid; s < S; s += nthr) anew[s] = 0.0f;
        const float* xt = xb + (size_t)t * D_SZ;
        for (int d = tid; d < D_SZ; d += nthr)
            xrow[d] = __expf(fminf(fmaxf(xt[d], -30.0f), 30.0f));
        __syncthreads();
        for (int e = tid; e < E; e += nthr) {
            float v = alpha[e_in[e]] * e_prob[e] * xrow[e_pdf[e]];
            atomicAdd(&anew[e_out[e]], v);
        }
        __syncthreads();
        float ps = 0.0f;
        for (int s = tid; s < S; s += nthr) ps += anew[s];
        #pragma unroll
        for (int off = 32; off > 0; off >>= 1) ps += __shfl_down(ps, off, 64);
        if ((tid & 63) == 0) red[tid >> 6] = ps;
        __syncthreads();
        if (tid < 64) {
            float v = (tid < 16) ? red[tid] : 0.0f;
            #pragma unroll
            for (int off = 8; off > 0; off >>= 1) v += __shfl_down(v, off, 64);
            if (tid == 0) red[16] = v;
        }
        __syncthreads();
        const float asum = red[16];
        const float inv = 1.0f / asum;
        for (int s = tid; s < S; s += nthr)
            alpha[s] = (anew[s] + coeff * leaky[s] * asum) * inv;
        logz += logf(asum);
        __syncthreads();
    }
    float fs = 0.0f;
    for (int s = tid; s < S; s += nthr) fs += alpha[s] * fin[s];
    #pragma unroll
    for (int off = 32; off > 0; off >>= 1) fs += __shfl_down(fs, off, 64);
    if ((tid & 63) == 0) red[tid >> 6] = fs;
    __syncthreads();
    if (tid < 64) {
        float v = (tid < 16) ? red[tid] : 0.0f;
        #pragma unroll
        for (int off = 8; off > 0; off >>= 1) v += __shfl_down(v, off, 64);
        if (tid == 0) part[blockIdx.x] = logz + logf(v);
    }
}

__global__ void combine_kernel(const float* __restrict__ part,
                               const int* __restrict__ lengths,
                               float* __restrict__ out)
{
    int tid = threadIdx.x;
    float v = 0.0f, l = 0.0f;
    if (tid < B_SZ) { v = part[tid] - part[B_SZ + tid]; l = (float)lengths[tid]; }
    #pragma unroll
    for (int off = 32; off > 0; off >>= 1) { v += __shfl_down(v, off, 64); l += __shfl_down(l, off, 64); }
    if (tid == 0) out[0] = v / l;
}

// ---------------------------------------------------------------------------
extern "C" void kernel_launch(void* const* d_in, const int* in_sizes, int n_in,
                              void* d_out, int out_size, void* d_ws, size_t ws_size,
                              hipStream_t stream)
{
    const float* x          = (const float*)d_in[0];
    const int*   lengths    = (const int*)  d_in[1];
    const int*   den_in_p   = (const int*)  d_in[2];
    const int*   den_out_p  = (const int*)  d_in[3];
    const int*   den_pdf_p  = (const int*)  d_in[4];
    const float* den_prob_p = (const float*)d_in[5];
    const float* den_leaky  = (const float*)d_in[6];
    const float* den_final  = (const float*)d_in[7];
    const int*   num_in_p   = (const int*)  d_in[8];
    const int*   num_out_p  = (const int*)  d_in[9];
    const int*   num_pdf_p  = (const int*)  d_in[10];
    const float* num_prob_p = (const float*)d_in[11];
    const float* num_leaky  = (const float*)d_in[12];
    const float* num_final  = (const float*)d_in[13];

    if (ws_size >= WS_BYTES) {
        char* ws = (char*)d_ws;
        hipLaunchKernelGGL(prep_init, dim3(1), dim3(256), 0, stream,
                           den_leaky, den_final, ws);
        hipLaunchKernelGGL(prep_hist, dim3((E_DEN + 255) / 256), dim3(256), 0, stream,
                           den_out_p, ws);
        hipLaunchKernelGGL(prep_scan, dim3(1), dim3(1024), 0, stream, ws);
        hipLaunchKernelGGL(prep_scatter, dim3((E_DEN + 255) / 256), dim3(256), 0, stream,
                           den_in_p, den_out_p, den_pdf_p, den_prob_p, ws);
        hipLaunchKernelGGL(prep_pack, dim3((EPAD + 255) / 256), dim3(256), 0, stream, ws);
        hipLaunchKernelGGL(chain_fwd2, dim3(2 * B_SZ), dim3(NTHR), 0, stream,
                           x, lengths, den_leaky, den_final,
                           num_in_p, num_out_p, num_pdf_p, num_prob_p,
                           num_leaky, num_final, ws);
        hipLaunchKernelGGL(combine2, dim3(1), dim3(64), 0, stream,
                           ws, lengths, (float*)d_out);
    } else {
        float* part = (float*)d_ws;
        hipLaunchKernelGGL(chain_fwd_kernel, dim3(2 * B_SZ), dim3(1024), 0, stream,
                           x, lengths,
                           den_in_p, den_out_p, den_pdf_p, den_prob_p, den_leaky, den_final,
                           num_in_p, num_out_p, num_pdf_p, num_prob_p, num_leaky, num_final,
                           part);
        hipLaunchKernelGGL(combine_kernel, dim3(1), dim3(64), 0, stream,
                           part, lengths, (float*)d_out);
    }
}

// Round 7
// 6142.867 us; speedup vs baseline: 1.8678x; 1.0707x over previous
//
#include <hip/hip_runtime.h>
#include <math.h>

// Problem constants (match setup_inputs in the reference).
#define B_SZ   32
#define T_SZ   400
#define D_SZ   2048
#define S_DEN  2000
#define E_DEN  60000
#define S_NUM  512
#define E_NUM  2048
#define DEN_C  1e-5f
#define NUM_C  1e-20f

#define NTHR   1024
#define EPT    64            // edges per thread (padded): 64*1024 = 65536
#define EPAD   65536

// Workspace layout (bytes, 64-aligned chunks).
#define REC_OFF     0u          // int4[E_DEN] CSR {in, pdf, prob, out} sorted by out
#define PACK_OFF    960000u     // uint2[EPAD] packed {in|pdf<<11|drow<<22, prob}
#define ROWPTR_OFF  1484288u    // int[S_DEN+1]
#define CNT_OFF     1492352u    // int[S_DEN]
#define CUR_OFF     1500352u    // int[S_DEN]
#define SROW_OFF    1508352u    // int[1024] per-thread start row
#define LF_OFF      1512448u    // float: sum(den_leaky*den_final)
#define TOTD_OFF    1512512u    // float[32]
#define TOTN_OFF    1512640u    // float[32]
#define WS_BYTES    1512768u

// ---------------- prep kernels ----------------
__global__ void prep_init(const float* __restrict__ den_leaky,
                          const float* __restrict__ den_final, char* ws) {
    int* cnt = (int*)(ws + CNT_OFF);
    int* cur = (int*)(ws + CUR_OFF);
    int* srow = (int*)(ws + SROW_OFF);
    __shared__ float part[256];
    int tid = threadIdx.x;
    float s = 0.f;
    for (int i = tid; i < S_DEN; i += 256) {
        cnt[i] = 0; cur[i] = 0;
        s += den_leaky[i] * den_final[i];
    }
    for (int i = tid; i < 1024; i += 256) srow[i] = 0;
    part[tid] = s;
    __syncthreads();
    for (int o = 128; o > 0; o >>= 1) { if (tid < o) part[tid] += part[tid + o]; __syncthreads(); }
    if (tid == 0) *(float*)(ws + LF_OFF) = part[0];
}

__global__ void prep_hist(const int* __restrict__ e_out, char* ws) {
    int e = blockIdx.x * blockDim.x + threadIdx.x;
    if (e < E_DEN) atomicAdd((int*)(ws + CNT_OFF) + e_out[e], 1);
}

__global__ __launch_bounds__(1024) void prep_scan(char* ws) {
    __shared__ int sb[2][2048];
    const int* cnt = (const int*)(ws + CNT_OFF);
    int* rowp = (int*)(ws + ROWPTR_OFF);
    int tid = threadIdx.x;
    for (int i = tid; i < 2048; i += 1024) sb[0][i] = (i < S_DEN) ? cnt[i] : 0;
    __syncthreads();
    int cur = 0;
    for (int d = 1; d < 2048; d <<= 1) {
        for (int i = tid; i < 2048; i += 1024)
            sb[1 - cur][i] = sb[cur][i] + ((i >= d) ? sb[cur][i - d] : 0);
        __syncthreads();
        cur ^= 1;
    }
    if (tid == 0) rowp[0] = 0;
    for (int i = tid; i < S_DEN; i += 1024) rowp[i + 1] = sb[cur][i];
}

__global__ void prep_scatter(const int* __restrict__ e_in, const int* __restrict__ e_out,
                             const int* __restrict__ e_pdf, const float* __restrict__ e_prob,
                             char* ws) {
    int e = blockIdx.x * blockDim.x + threadIdx.x;
    if (e >= E_DEN) return;
    const int* rowp = (const int*)(ws + ROWPTR_OFF);
    int* cur = (int*)(ws + CUR_OFF);
    int4* recs = (int4*)(ws + REC_OFF);
    int o = e_out[e];
    int pos = rowp[o] + atomicAdd(&cur[o], 1);
    int4 r;
    r.x = e_in[e]; r.y = e_pdf[e];
    r.z = __float_as_int(e_prob[e]);
    r.w = o;
    recs[pos] = r;
}

// Pack to 8B records with row-advance deltas + per-thread start rows.
// Pads to EPAD with dummy records (prob=0, delta=0) so the main loop has a
// fixed trip count (ws is re-poisoned each launch, so dummies must be written).
__global__ void prep_pack(char* ws) {
    int k = blockIdx.x * blockDim.x + threadIdx.x;
    if (k >= EPAD) return;
    uint2* pk = (uint2*)(ws + PACK_OFF);
    if (k >= E_DEN) { pk[k] = make_uint2(0u, 0u); return; }
    const int4* r4 = (const int4*)(ws + REC_OFF);
    int4 r = r4[k];
    int out = r.w;
    int nxt = (k + 1 < E_DEN) ? r4[k + 1].w : out;   // last edge: delta 0
    unsigned d = (unsigned)(nxt - out);
    if (d > 1023u) d = 1023u;                        // unreachable with this graph
    pk[k] = make_uint2((unsigned)r.x | ((unsigned)r.y << 11) | (d << 22),
                       (unsigned)r.z);
    if ((k & (EPT - 1)) == 0) ((int*)(ws + SROW_OFF))[k / EPT] = out;
}

// ---------------- main kernel: 32 den blocks + 32 num blocks, no grid sync ----
__global__ __launch_bounds__(NTHR, 4) void chain_fwd2(
    const float* __restrict__ x, const int* __restrict__ lengths,
    const float* __restrict__ den_leaky, const float* __restrict__ den_final,
    const int* __restrict__ num_in, const int* __restrict__ num_out,
    const int* __restrict__ num_pdf, const float* __restrict__ num_prob,
    const float* __restrict__ num_leaky, const float* __restrict__ num_final,
    char* __restrict__ ws)
{
    __shared__ float alpha[2048];
    __shared__ float xrow[2048];
    __shared__ float anew[2048];
    __shared__ float red[34];
    const int tid = threadIdx.x;

    if (blockIdx.x < B_SZ) {
        // =============== den: one block per utterance, fully LDS-resident ========
        const int b = blockIdx.x;
        const uint4* __restrict__ pk4 = (const uint4*)(ws + PACK_OFF); // 2 recs/uint4
        const int*   __restrict__ srow = (const int*)(ws + SROW_OFF);
        float* __restrict__ totd = (float*)(ws + TOTD_OFF);
        const float LF = *(const float*)(ws + LF_OFF);
        const int len = lengths[b];
        const float* xb = x + (size_t)b * T_SZ * D_SZ;

        // Hoisted per-state constants (invariant over t).
        const float l0c = (tid < S_DEN) ? DEN_C * den_leaky[tid] : 0.f;
        const float l1c = (tid + 1024 < S_DEN) ? DEN_C * den_leaky[tid + 1024] : 0.f;
        const float f0c = (tid < S_DEN) ? den_final[tid] : 0.f;
        const float f1c = (tid + 1024 < S_DEN) ? den_final[tid + 1024] : 0.f;

        // adash0 = alpha0 (asum=1): mass on state 0 + leaky.
        alpha[tid]        = l0c + (tid == 0 ? 1.f : 0.f);
        alpha[tid + 1024] = l1c;
        anew[tid] = 0.f; anew[tid + 1024] = 0.f;
        // Stage xrow(0).
        xrow[tid]        = __expf(fminf(fmaxf(xb[tid],        -30.f), 30.f));
        xrow[tid + 1024] = __expf(fminf(fmaxf(xb[tid + 1024], -30.f), 30.f));

        const int qb = tid * (EPT / 2);   // uint4 index base: 64 recs = 32 uint4
        const int row0 = srow[tid];
        float logz = 0.f;
        float tot = 0.f;
        // Batch-0 records prefetched across step boundaries.
        uint4 c0 = pk4[qb + 0], c1 = pk4[qb + 1], c2 = pk4[qb + 2], c3 = pk4[qb + 3];
        __syncthreads();

        for (int t = 0; t < len; ++t) {
            // Prefetch x(t+1) into registers (consumed in Phase D).
            const int tn = (t + 1 < len) ? t + 1 : t;
            const float* xq = xb + (size_t)tn * D_SZ;
            const float xn0 = xq[tid];
            const float xn1 = xq[tid + 1024];

            // Phase B: 8 batches x 8 edges; records double-buffered in registers
            // with wraparound prefetch (bt==7 reloads batch 0 for step t+1).
            float acc = 0.f;
            int row = row0;
            #pragma unroll
            for (int bt = 0; bt < 8; ++bt) {
                const int nq = qb + (((bt + 1) & 7) * 4);
                uint4 n0 = pk4[nq], n1 = pk4[nq + 1], n2 = pk4[nq + 2], n3 = pk4[nq + 3];
                const unsigned w[8] = {c0.x, c0.z, c1.x, c1.z, c2.x, c2.z, c3.x, c3.z};
                const unsigned p[8] = {c0.y, c0.w, c1.y, c1.w, c2.y, c2.w, c3.y, c3.w};
                float av[8], xv[8];
                #pragma unroll
                for (int i = 0; i < 8; ++i) av[i] = alpha[w[i] & 2047u];
                #pragma unroll
                for (int i = 0; i < 8; ++i) xv[i] = xrow[(w[i] >> 11) & 2047u];
                #pragma unroll
                for (int i = 0; i < 8; ++i) {
                    acc = __fmaf_rn(av[i] * __uint_as_float(p[i]), xv[i], acc);
                    const unsigned d = w[i] >> 22;
                    if (d) { atomicAdd(&anew[row], acc); acc = 0.f; row += (int)d; }
                }
                c0 = n0; c1 = n1; c2 = n2; c3 = n3;
            }
            if (acc != 0.f) atomicAdd(&anew[row], acc);
            __syncthreads();                             // B-end

            // Phase C: per-wave partials, one barrier, broadcast sum.
            const bool last = (t == len - 1);
            float ps = anew[tid] + anew[tid + 1024];
            #pragma unroll
            for (int o = 32; o > 0; o >>= 1) ps += __shfl_down(ps, o, 64);
            if (last) {
                float pf = anew[tid] * f0c + anew[tid + 1024] * f1c;
                #pragma unroll
                for (int o = 32; o > 0; o >>= 1) pf += __shfl_down(pf, o, 64);
                if ((tid & 63) == 0) red[16 + (tid >> 6)] = pf;
            }
            if ((tid & 63) == 0) red[tid >> 6] = ps;
            __syncthreads();                             // C barrier

            float asum = 0.f;
            #pragma unroll
            for (int i = 0; i < 16; ++i) asum += red[i];
            const float inv = 1.f / asum;

            // Phase D: alpha <- adash; zero own anew; stage xrow(t+1).
            alpha[tid]        = __fmaf_rn(anew[tid],        inv, l0c);
            alpha[tid + 1024] = __fmaf_rn(anew[tid + 1024], inv, l1c);
            anew[tid] = 0.f; anew[tid + 1024] = 0.f;
            xrow[tid]        = __expf(fminf(fmaxf(xn0, -30.f), 30.f));
            xrow[tid + 1024] = __expf(fminf(fmaxf(xn1, -30.f), 30.f));
            if (last && tid == 0) {
                float pfin = 0.f;
                #pragma unroll
                for (int i = 0; i < 16; ++i) pfin += red[16 + i];
                tot = logz + logf(asum) + logf(__fmaf_rn(pfin, inv, DEN_C * LF));
            }
            logz += logf(asum);
            __syncthreads();                             // D-end
        }
        if (tid == 0) totd[b] = tot;
    } else {
        // =============== num: one block per utterance, LDS-local =================
        const int b = blockIdx.x - B_SZ;
        float* nalpha = alpha;             // [512]
        float* nanew  = anew;              // [512]
        float* totn   = (float*)(ws + TOTN_OFF);

        const int len = lengths[b];
        const float lk = (tid < S_NUM) ? num_leaky[b * S_NUM + tid] : 0.f;
        const float fn = (tid < S_NUM) ? num_final[b * S_NUM + tid] : 0.f;
        const int*   ein  = num_in   + b * E_NUM;
        const int*   eout = num_out  + b * E_NUM;
        const int*   epdf = num_pdf  + b * E_NUM;
        const float* eprb = num_prob + b * E_NUM;
        const float* xb = x + (size_t)b * T_SZ * D_SZ;

        if (tid < S_NUM) nalpha[tid] = NUM_C * lk + (tid == 0 ? 1.f : 0.f);
        float logz = 0.f;
        __syncthreads();

        for (int t = 0; t < len; ++t) {
            if (tid < S_NUM) nanew[tid] = 0.f;
            const float* xp = xb + (size_t)t * D_SZ;
            xrow[tid]        = __expf(fminf(fmaxf(xp[tid],        -30.f), 30.f));
            xrow[tid + 1024] = __expf(fminf(fmaxf(xp[tid + 1024], -30.f), 30.f));
            __syncthreads();
            for (int e = tid; e < E_NUM; e += NTHR) {
                float v = nalpha[ein[e]] * eprb[e] * xrow[epdf[e]];
                atomicAdd(&nanew[eout[e]], v);
            }
            __syncthreads();
            float ps = (tid < S_NUM) ? nanew[tid] : 0.f;
            #pragma unroll
            for (int o = 32; o > 0; o >>= 1) ps += __shfl_down(ps, o, 64);
            if ((tid & 63) == 0) red[tid >> 6] = ps;
            __syncthreads();
            if (tid < 64) {
                float v2 = (tid < 16) ? red[tid] : 0.f;
                #pragma unroll
                for (int o = 8; o > 0; o >>= 1) v2 += __shfl_down(v2, o, 64);
                if (tid == 0) red[32] = v2;
            }
            __syncthreads();
            const float asum = red[32];
            if (tid < S_NUM)
                nalpha[tid] = __fmaf_rn(NUM_C * lk, asum, nanew[tid]) * (1.f / asum);
            logz += logf(asum);
            __syncthreads();
        }
        float fs = (tid < S_NUM) ? nalpha[tid] * fn : 0.f;
        #pragma unroll
        for (int o = 32; o > 0; o >>= 1) fs += __shfl_down(fs, o, 64);
        if ((tid & 63) == 0) red[tid >> 6] = fs;
        __syncthreads();
        if (tid < 64) {
            float v2 = (tid < 16) ? red[tid] : 0.f;
            #pragma unroll
            for (int o = 8; o > 0; o >>= 1) v2 += __shfl_down(v2, o, 64);
            if (tid == 0) totn[b] = logz + logf(v2);
        }
    }
}

__global__ void combine2(const char* __restrict__ ws, const int* __restrict__ lengths,
                         float* __restrict__ out) {
    const float* totd = (const float*)(ws + TOTD_OFF);
    const float* totn = (const float*)(ws + TOTN_OFF);
    int tid = threadIdx.x;
    float v = 0.f, l = 0.f;
    if (tid < B_SZ) { v = totd[tid] - totn[tid]; l = (float)lengths[tid]; }
    #pragma unroll
    for (int o = 32; o > 0; o >>= 1) { v += __shfl_down(v, o, 64); l += __shfl_down(l, o, 64); }
    if (tid == 0) out[0] = v / l;
}

// ===================== round-1 fallback (used only if ws too small) ==========
__global__ __launch_bounds__(1024) void chain_fwd_kernel(
    const float* __restrict__ x, const int* __restrict__ lengths,
    const int* __restrict__ den_in, const int* __restrict__ den_out,
    const int* __restrict__ den_pdf, const float* __restrict__ den_prob,
    const float* __restrict__ den_leaky, const float* __restrict__ den_final,
    const int* __restrict__ num_in, const int* __restrict__ num_out,
    const int* __restrict__ num_pdf, const float* __restrict__ num_prob,
    const float* __restrict__ num_leaky, const float* __restrict__ num_final,
    float* __restrict__ part)
{
    __shared__ float xrow[D_SZ];
    __shared__ float alpha[S_DEN];
    __shared__ float anew[S_DEN];
    __shared__ float red[17];
    const int tid = threadIdx.x;
    const int nthr = 1024;
    const bool is_den = blockIdx.x < B_SZ;
    const int b = blockIdx.x & (B_SZ - 1);
    int S, E;
    const int *e_in, *e_out, *e_pdf;
    const float *e_prob, *leaky, *fin;
    float coeff;
    if (is_den) {
        S = S_DEN; E = E_DEN;
        e_in = den_in; e_out = den_out; e_pdf = den_pdf; e_prob = den_prob;
        leaky = den_leaky; fin = den_final; coeff = DEN_C;
    } else {
        S = S_NUM; E = E_NUM;
        e_in = num_in + b * E_NUM; e_out = num_out + b * E_NUM;
        e_pdf = num_pdf + b * E_NUM; e_prob = num_prob + b * E_NUM;
        leaky = num_leaky + b * S_NUM; fin = num_final + b * S_NUM;
        coeff = NUM_C;
    }
    const int len = lengths[b];
    const float* xb = x + (size_t)b * T_SZ * D_SZ;
    for (int s = tid; s < S; s += nthr)
        alpha[s] = coeff * leaky[s] + (s == 0 ? 1.0f : 0.0f);
    float logz = 0.0f;
    for (int t = 0; t < len; ++t) {
        for (int s = tid; s < S; s += nthr) anew[s] = 0.0f;
        const float* xt = xb + (size_t)t * D_SZ;
        for (int d = tid; d < D_SZ; d += nthr)
            xrow[d] = __expf(fminf(fmaxf(xt[d], -30.0f), 30.0f));
        __syncthreads();
        for (int e = tid; e < E; e += nthr) {
            float v = alpha[e_in[e]] * e_prob[e] * xrow[e_pdf[e]];
            atomicAdd(&anew[e_out[e]], v);
        }
        __syncthreads();
        float ps = 0.0f;
        for (int s = tid; s < S; s += nthr) ps += anew[s];
        #pragma unroll
        for (int off = 32; off > 0; off >>= 1) ps += __shfl_down(ps, off, 64);
        if ((tid & 63) == 0) red[tid >> 6] = ps;
        __syncthreads();
        if (tid < 64) {
            float v = (tid < 16) ? red[tid] : 0.0f;
            #pragma unroll
            for (int off = 8; off > 0; off >>= 1) v += __shfl_down(v, off, 64);
            if (tid == 0) red[16] = v;
        }
        __syncthreads();
        const float asum = red[16];
        const float inv = 1.0f / asum;
        for (int s = tid; s < S; s += nthr)
            alpha[s] = (anew[s] + coeff * leaky[s] * asum) * inv;
        logz += logf(asum);
        __syncthreads();
    }
    float fs = 0.0f;
    for (int s = tid; s < S; s += nthr) fs += alpha[s] * fin[s];
    #pragma unroll
    for (int off = 32; off > 0; off >>= 1) fs += __shfl_down(fs, off, 64);
    if ((tid & 63) == 0) red[tid >> 6] = fs;
    __syncthreads();
    if (tid < 64) {
        float v = (tid < 16) ? red[tid] : 0.0f;
        #pragma unroll
        for (int off = 8; off > 0; off >>= 1) v += __shfl_down(v, off, 64);
        if (tid == 0) part[blockIdx.x] = logz + logf(v);
    }
}

__global__ void combine_kernel(const float* __restrict__ part,
                               const int* __restrict__ lengths,
                               float* __restrict__ out)
{
    int tid = threadIdx.x;
    float v = 0.0f, l = 0.0f;
    if (tid < B_SZ) { v = part[tid] - part[B_SZ + tid]; l = (float)lengths[tid]; }
    #pragma unroll
    for (int off = 32; off > 0; off >>= 1) { v += __shfl_down(v, off, 64); l += __shfl_down(l, off, 64); }
    if (tid == 0) out[0] = v / l;
}

// ---------------------------------------------------------------------------
extern "C" void kernel_launch(void* const* d_in, const int* in_sizes, int n_in,
                              void* d_out, int out_size, void* d_ws, size_t ws_size,
                              hipStream_t stream)
{
    const float* x          = (const float*)d_in[0];
    const int*   lengths    = (const int*)  d_in[1];
    const int*   den_in_p   = (const int*)  d_in[2];
    const int*   den_out_p  = (const int*)  d_in[3];
    const int*   den_pdf_p  = (const int*)  d_in[4];
    const float* den_prob_p = (const float*)d_in[5];
    const float* den_leaky  = (const float*)d_in[6];
    const float* den_final  = (const float*)d_in[7];
    const int*   num_in_p   = (const int*)  d_in[8];
    const int*   num_out_p  = (const int*)  d_in[9];
    const int*   num_pdf_p  = (const int*)  d_in[10];
    const float* num_prob_p = (const float*)d_in[11];
    const float* num_leaky  = (const float*)d_in[12];
    const float* num_final  = (const float*)d_in[13];

    if (ws_size >= WS_BYTES) {
        char* ws = (char*)d_ws;
        hipLaunchKernelGGL(prep_init, dim3(1), dim3(256), 0, stream,
                           den_leaky, den_final, ws);
        hipLaunchKernelGGL(prep_hist, dim3((E_DEN + 255) / 256), dim3(256), 0, stream,
                           den_out_p, ws);
        hipLaunchKernelGGL(prep_scan, dim3(1), dim3(1024), 0, stream, ws);
        hipLaunchKernelGGL(prep_scatter, dim3((E_DEN + 255) / 256), dim3(256), 0, stream,
                           den_in_p, den_out_p, den_pdf_p, den_prob_p, ws);
        hipLaunchKernelGGL(prep_pack, dim3((EPAD + 255) / 256), dim3(256), 0, stream, ws);
        hipLaunchKernelGGL(chain_fwd2, dim3(2 * B_SZ), dim3(NTHR), 0, stream,
                           x, lengths, den_leaky, den_final,
                           num_in_p, num_out_p, num_pdf_p, num_prob_p,
                           num_leaky, num_final, ws);
        hipLaunchKernelGGL(combine2, dim3(1), dim3(64), 0, stream,
                           ws, lengths, (float*)d_out);
    } else {
        float* part = (float*)d_ws;
        hipLaunchKernelGGL(chain_fwd_kernel, dim3(2 * B_SZ), dim3(1024), 0, stream,
                           x, lengths,
                           den_in_p, den_out_p, den_pdf_p, den_prob_p, den_leaky, den_final,
                           num_in_p, num_out_p, num_pdf_p, num_prob_p, num_leaky, num_final,
                           part);
        hipLaunchKernelGGL(combine_kernel, dim3(1), dim3(64), 0, stream,
                           part, lengths, (float*)d_out);
    }
}

// Round 8
// 6091.668 us; speedup vs baseline: 1.8835x; 1.0084x over previous
//
#include <hip/hip_runtime.h>
#include <math.h>

// Problem constants (match setup_inputs in the reference).
#define B_SZ   32
#define T_SZ   400
#define D_SZ   2048
#define S_DEN  2000
#define E_DEN  60000
#define S_NUM  512
#define E_NUM  2048
#define DEN_C  1e-5f
#define NUM_C  1e-20f

#define NTHR   1024
#define EPT    64            // edges per thread (padded): 64*1024 = 65536
#define EPAD   65536

// Workspace layout (bytes, 64-aligned chunks).
#define REC_OFF     0u          // int4[E_DEN] CSR {in, pdf, prob, out} sorted by out
#define PACK_OFF    960000u     // uint2[EPAD] packed {in|pdf<<11|drow<<22, prob}
#define ROWPTR_OFF  1484288u    // int[S_DEN+1]
#define CNT_OFF     1492352u    // int[S_DEN]
#define CUR_OFF     1500352u    // int[S_DEN]
#define SROW_OFF    1508352u    // int[1024] per-thread start row
#define LF_OFF      1512448u    // float: sum(den_leaky*den_final)
#define TOTD_OFF    1512512u    // float[32]
#define TOTN_OFF    1512640u    // float[32]
#define WS_BYTES    1512768u

// ---------------- prep kernels ----------------
__global__ void prep_init(const float* __restrict__ den_leaky,
                          const float* __restrict__ den_final, char* ws) {
    int* cnt = (int*)(ws + CNT_OFF);
    int* cur = (int*)(ws + CUR_OFF);
    int* srow = (int*)(ws + SROW_OFF);
    __shared__ float part[256];
    int tid = threadIdx.x;
    float s = 0.f;
    for (int i = tid; i < S_DEN; i += 256) {
        cnt[i] = 0; cur[i] = 0;
        s += den_leaky[i] * den_final[i];
    }
    for (int i = tid; i < 1024; i += 256) srow[i] = 0;
    part[tid] = s;
    __syncthreads();
    for (int o = 128; o > 0; o >>= 1) { if (tid < o) part[tid] += part[tid + o]; __syncthreads(); }
    if (tid == 0) *(float*)(ws + LF_OFF) = part[0];
}

__global__ void prep_hist(const int* __restrict__ e_out, char* ws) {
    int e = blockIdx.x * blockDim.x + threadIdx.x;
    if (e < E_DEN) atomicAdd((int*)(ws + CNT_OFF) + e_out[e], 1);
}

__global__ __launch_bounds__(1024) void prep_scan(char* ws) {
    __shared__ int sb[2][2048];
    const int* cnt = (const int*)(ws + CNT_OFF);
    int* rowp = (int*)(ws + ROWPTR_OFF);
    int tid = threadIdx.x;
    for (int i = tid; i < 2048; i += 1024) sb[0][i] = (i < S_DEN) ? cnt[i] : 0;
    __syncthreads();
    int cur = 0;
    for (int d = 1; d < 2048; d <<= 1) {
        for (int i = tid; i < 2048; i += 1024)
            sb[1 - cur][i] = sb[cur][i] + ((i >= d) ? sb[cur][i - d] : 0);
        __syncthreads();
        cur ^= 1;
    }
    if (tid == 0) rowp[0] = 0;
    for (int i = tid; i < S_DEN; i += 1024) rowp[i + 1] = sb[cur][i];
}

__global__ void prep_scatter(const int* __restrict__ e_in, const int* __restrict__ e_out,
                             const int* __restrict__ e_pdf, const float* __restrict__ e_prob,
                             char* ws) {
    int e = blockIdx.x * blockDim.x + threadIdx.x;
    if (e >= E_DEN) return;
    const int* rowp = (const int*)(ws + ROWPTR_OFF);
    int* cur = (int*)(ws + CUR_OFF);
    int4* recs = (int4*)(ws + REC_OFF);
    int o = e_out[e];
    int pos = rowp[o] + atomicAdd(&cur[o], 1);
    int4 r;
    r.x = e_in[e]; r.y = e_pdf[e];
    r.z = __float_as_int(e_prob[e]);
    r.w = o;
    recs[pos] = r;
}

// Pack to 8B records with row-advance deltas + per-thread start rows.
// Pads to EPAD with dummy records (prob=0, delta=0) so the main loop has a
// fixed trip count (ws is re-poisoned each launch, so dummies must be written).
__global__ void prep_pack(char* ws) {
    int k = blockIdx.x * blockDim.x + threadIdx.x;
    if (k >= EPAD) return;
    uint2* pk = (uint2*)(ws + PACK_OFF);
    if (k >= E_DEN) { pk[k] = make_uint2(0u, 0u); return; }
    const int4* r4 = (const int4*)(ws + REC_OFF);
    int4 r = r4[k];
    int out = r.w;
    int nxt = (k + 1 < E_DEN) ? r4[k + 1].w : out;   // last edge: delta 0
    unsigned d = (unsigned)(nxt - out);
    if (d > 1023u) d = 1023u;                        // unreachable with this graph
    pk[k] = make_uint2((unsigned)r.x | ((unsigned)r.y << 11) | (d << 22),
                       (unsigned)r.z);
    if ((k & (EPT - 1)) == 0) ((int*)(ws + SROW_OFF))[k / EPT] = out;
}

// ---------------- main kernel: 32 den blocks + 32 num blocks, no grid sync ----
__global__ __launch_bounds__(NTHR, 4) void chain_fwd2(
    const float* __restrict__ x, const int* __restrict__ lengths,
    const float* __restrict__ den_leaky, const float* __restrict__ den_final,
    const int* __restrict__ num_in, const int* __restrict__ num_out,
    const int* __restrict__ num_pdf, const float* __restrict__ num_prob,
    const float* __restrict__ num_leaky, const float* __restrict__ num_final,
    char* __restrict__ ws)
{
    __shared__ float alpha[2048];
    __shared__ float xrow[2048];
    __shared__ float anew[2048];
    __shared__ float red[34];
    const int tid = threadIdx.x;

    if (blockIdx.x < B_SZ) {
        // =============== den: one block per utterance, fully LDS-resident ========
        const int b = blockIdx.x;
        const uint4* __restrict__ pk4 = (const uint4*)(ws + PACK_OFF); // 2 recs/uint4
        const int*   __restrict__ srow = (const int*)(ws + SROW_OFF);
        float* __restrict__ totd = (float*)(ws + TOTD_OFF);
        const float LF = *(const float*)(ws + LF_OFF);
        const int len = lengths[b];
        const float* xb = x + (size_t)b * T_SZ * D_SZ;

        // Hoisted per-state constants (invariant over t).
        const float l0c = (tid < S_DEN) ? DEN_C * den_leaky[tid] : 0.f;
        const float l1c = (tid + 1024 < S_DEN) ? DEN_C * den_leaky[tid + 1024] : 0.f;
        const float f0c = (tid < S_DEN) ? den_final[tid] : 0.f;
        const float f1c = (tid + 1024 < S_DEN) ? den_final[tid + 1024] : 0.f;

        // adash0 = alpha0 (asum=1): mass on state 0 + leaky.
        alpha[tid]        = l0c + (tid == 0 ? 1.f : 0.f);
        alpha[tid + 1024] = l1c;
        anew[tid] = 0.f; anew[tid + 1024] = 0.f;
        // Stage xrow(0).
        xrow[tid]        = __expf(fminf(fmaxf(xb[tid],        -30.f), 30.f));
        xrow[tid + 1024] = __expf(fminf(fmaxf(xb[tid + 1024], -30.f), 30.f));

        const int qb = tid * (EPT / 2);   // uint4 index base: 64 recs = 32 uint4
        const int row0 = srow[tid];
        float logz = 0.f;
        float tot = 0.f;
        // Superbatch-0 records prefetched across step boundaries (16 edges).
        uint4 c0 = pk4[qb + 0], c1 = pk4[qb + 1], c2 = pk4[qb + 2], c3 = pk4[qb + 3];
        uint4 c4 = pk4[qb + 4], c5 = pk4[qb + 5], c6 = pk4[qb + 6], c7 = pk4[qb + 7];
        __syncthreads();

        for (int t = 0; t < len; ++t) {
            // Prefetch x(t+1) into registers (consumed in Phase D).
            const int tn = (t + 1 < len) ? t + 1 : t;
            const float* xq = xb + (size_t)tn * D_SZ;
            const float xn0 = xq[tid];
            const float xn1 = xq[tid + 1024];

            // Phase B: 4 superbatches x 16 edges; 32 LDS gathers in flight per
            // wave before the consume chain; wraparound prefetch of the next
            // superbatch (sb==3 reloads sb 0 for step t+1). asum partial (psum)
            // folded into the row flushes.
            float acc = 0.f, psum = 0.f;
            int row = row0;
            #pragma unroll
            for (int sb = 0; sb < 4; ++sb) {
                const int nq = qb + (((sb + 1) & 3) * 8);
                uint4 n0 = pk4[nq + 0], n1 = pk4[nq + 1], n2 = pk4[nq + 2], n3 = pk4[nq + 3];
                uint4 n4 = pk4[nq + 4], n5 = pk4[nq + 5], n6 = pk4[nq + 6], n7 = pk4[nq + 7];
                const unsigned w[16] = {c0.x, c0.z, c1.x, c1.z, c2.x, c2.z, c3.x, c3.z,
                                        c4.x, c4.z, c5.x, c5.z, c6.x, c6.z, c7.x, c7.z};
                const unsigned p[16] = {c0.y, c0.w, c1.y, c1.w, c2.y, c2.w, c3.y, c3.w,
                                        c4.y, c4.w, c5.y, c5.w, c6.y, c6.w, c7.y, c7.w};
                float av[16], xv[16];
                #pragma unroll
                for (int i = 0; i < 16; ++i) av[i] = alpha[w[i] & 2047u];
                #pragma unroll
                for (int i = 0; i < 16; ++i) xv[i] = xrow[(w[i] >> 11) & 2047u];
                #pragma unroll
                for (int i = 0; i < 16; ++i) {
                    acc = __fmaf_rn(av[i] * __uint_as_float(p[i]), xv[i], acc);
                    const unsigned d = w[i] >> 22;
                    if (d) { psum += acc; atomicAdd(&anew[row], acc); acc = 0.f; row += (int)d; }
                }
                c0 = n0; c1 = n1; c2 = n2; c3 = n3;
                c4 = n4; c5 = n5; c6 = n6; c7 = n7;
            }
            psum += acc;
            if (acc != 0.f) atomicAdd(&anew[row], acc);

            // Wave-reduce psum; one barrier covers anew + red completion.
            #pragma unroll
            for (int o = 32; o > 0; o >>= 1) psum += __shfl_down(psum, o, 64);
            if ((tid & 63) == 0) red[tid >> 6] = psum;
            __syncthreads();                             // barrier 1

            float asum = 0.f;
            #pragma unroll
            for (int i = 0; i < 16; ++i) asum += red[i];
            const float inv = 1.f / asum;

            const bool last = (t == len - 1);            // block-uniform
            if (last) {
                float pf = anew[tid] * f0c + anew[tid + 1024] * f1c;
                #pragma unroll
                for (int o = 32; o > 0; o >>= 1) pf += __shfl_down(pf, o, 64);
                if ((tid & 63) == 0) red[16 + (tid >> 6)] = pf;
                __syncthreads();
                if (tid == 0) {
                    float pfin = 0.f;
                    #pragma unroll
                    for (int i = 0; i < 16; ++i) pfin += red[16 + i];
                    tot = logz + logf(asum) + logf(__fmaf_rn(pfin, inv, DEN_C * LF));
                }
            }

            // Phase D: alpha <- adash; zero own anew; stage xrow(t+1).
            alpha[tid]        = __fmaf_rn(anew[tid],        inv, l0c);
            alpha[tid + 1024] = __fmaf_rn(anew[tid + 1024], inv, l1c);
            anew[tid] = 0.f; anew[tid + 1024] = 0.f;
            xrow[tid]        = __expf(fminf(fmaxf(xn0, -30.f), 30.f));
            xrow[tid + 1024] = __expf(fminf(fmaxf(xn1, -30.f), 30.f));
            logz += logf(asum);
            __syncthreads();                             // barrier 2
        }
        if (tid == 0) totd[b] = tot;
    } else {
        // =============== num: one block per utterance, LDS-local =================
        const int b = blockIdx.x - B_SZ;
        float* nalpha = alpha;             // [512]
        float* nanew  = anew;              // [512]
        float* totn   = (float*)(ws + TOTN_OFF);

        const int len = lengths[b];
        const float lk = (tid < S_NUM) ? num_leaky[b * S_NUM + tid] : 0.f;
        const float fn = (tid < S_NUM) ? num_final[b * S_NUM + tid] : 0.f;
        const int*   ein  = num_in   + b * E_NUM;
        const int*   eout = num_out  + b * E_NUM;
        const int*   epdf = num_pdf  + b * E_NUM;
        const float* eprb = num_prob + b * E_NUM;
        const float* xb = x + (size_t)b * T_SZ * D_SZ;

        if (tid < S_NUM) nalpha[tid] = NUM_C * lk + (tid == 0 ? 1.f : 0.f);
        float logz = 0.f;
        __syncthreads();

        for (int t = 0; t < len; ++t) {
            if (tid < S_NUM) nanew[tid] = 0.f;
            const float* xp = xb + (size_t)t * D_SZ;
            xrow[tid]        = __expf(fminf(fmaxf(xp[tid],        -30.f), 30.f));
            xrow[tid + 1024] = __expf(fminf(fmaxf(xp[tid + 1024], -30.f), 30.f));
            __syncthreads();
            for (int e = tid; e < E_NUM; e += NTHR) {
                float v = nalpha[ein[e]] * eprb[e] * xrow[epdf[e]];
                atomicAdd(&nanew[eout[e]], v);
            }
            __syncthreads();
            float ps = (tid < S_NUM) ? nanew[tid] : 0.f;
            #pragma unroll
            for (int o = 32; o > 0; o >>= 1) ps += __shfl_down(ps, o, 64);
            if ((tid & 63) == 0) red[tid >> 6] = ps;
            __syncthreads();
            if (tid < 64) {
                float v2 = (tid < 16) ? red[tid] : 0.f;
                #pragma unroll
                for (int o = 8; o > 0; o >>= 1) v2 += __shfl_down(v2, o, 64);
                if (tid == 0) red[32] = v2;
            }
            __syncthreads();
            const float asum = red[32];
            if (tid < S_NUM)
                nalpha[tid] = __fmaf_rn(NUM_C * lk, asum, nanew[tid]) * (1.f / asum);
            logz += logf(asum);
            __syncthreads();
        }
        float fs = (tid < S_NUM) ? nalpha[tid] * fn : 0.f;
        #pragma unroll
        for (int o = 32; o > 0; o >>= 1) fs += __shfl_down(fs, o, 64);
        if ((tid & 63) == 0) red[tid >> 6] = fs;
        __syncthreads();
        if (tid < 64) {
            float v2 = (tid < 16) ? red[tid] : 0.f;
            #pragma unroll
            for (int o = 8; o > 0; o >>= 1) v2 += __shfl_down(v2, o, 64);
            if (tid == 0) totn[b] = logz + logf(v2);
        }
    }
}

__global__ void combine2(const char* __restrict__ ws, const int* __restrict__ lengths,
                         float* __restrict__ out) {
    const float* totd = (const float*)(ws + TOTD_OFF);
    const float* totn = (const float*)(ws + TOTN_OFF);
    int tid = threadIdx.x;
    float v = 0.f, l = 0.f;
    if (tid < B_SZ) { v = totd[tid] - totn[tid]; l = (float)lengths[tid]; }
    #pragma unroll
    for (int o = 32; o > 0; o >>= 1) { v += __shfl_down(v, o, 64); l += __shfl_down(l, o, 64); }
    if (tid == 0) out[0] = v / l;
}

// ===================== round-1 fallback (used only if ws too small) ==========
__global__ __launch_bounds__(1024) void chain_fwd_kernel(
    const float* __restrict__ x, const int* __restrict__ lengths,
    const int* __restrict__ den_in, const int* __restrict__ den_out,
    const int* __restrict__ den_pdf, const float* __restrict__ den_prob,
    const float* __restrict__ den_leaky, const float* __restrict__ den_final,
    const int* __restrict__ num_in, const int* __restrict__ num_out,
    const int* __restrict__ num_pdf, const float* __restrict__ num_prob,
    const float* __restrict__ num_leaky, const float* __restrict__ num_final,
    float* __restrict__ part)
{
    __shared__ float xrow[D_SZ];
    __shared__ float alpha[S_DEN];
    __shared__ float anew[S_DEN];
    __shared__ float red[17];
    const int tid = threadIdx.x;
    const int nthr = 1024;
    const bool is_den = blockIdx.x < B_SZ;
    const int b = blockIdx.x & (B_SZ - 1);
    int S, E;
    const int *e_in, *e_out, *e_pdf;
    const float *e_prob, *leaky, *fin;
    float coeff;
    if (is_den) {
        S = S_DEN; E = E_DEN;
        e_in = den_in; e_out = den_out; e_pdf = den_pdf; e_prob = den_prob;
        leaky = den_leaky; fin = den_final; coeff = DEN_C;
    } else {
        S = S_NUM; E = E_NUM;
        e_in = num_in + b * E_NUM; e_out = num_out + b * E_NUM;
        e_pdf = num_pdf + b * E_NUM; e_prob = num_prob + b * E_NUM;
        leaky = num_leaky + b * S_NUM; fin = num_final + b * S_NUM;
        coeff = NUM_C;
    }
    const int len = lengths[b];
    const float* xb = x + (size_t)b * T_SZ * D_SZ;
    for (int s = tid; s < S; s += nthr)
        alpha[s] = coeff * leaky[s] + (s == 0 ? 1.0f : 0.0f);
    float logz = 0.0f;
    for (int t = 0; t < len; ++t) {
        for (int s = tid; s < S; s += nthr) anew[s] = 0.0f;
        const float* xt = xb + (size_t)t * D_SZ;
        for (int d = tid; d < D_SZ; d += nthr)
            xrow[d] = __expf(fminf(fmaxf(xt[d], -30.0f), 30.0f));
        __syncthreads();
        for (int e = tid; e < E; e += nthr) {
            float v = alpha[e_in[e]] * e_prob[e] * xrow[e_pdf[e]];
            atomicAdd(&anew[e_out[e]], v);
        }
        __syncthreads();
        float ps = 0.0f;
        for (int s = tid; s < S; s += nthr) ps += anew[s];
        #pragma unroll
        for (int off = 32; off > 0; off >>= 1) ps += __shfl_down(ps, off, 64);
        if ((tid & 63) == 0) red[tid >> 6] = ps;
        __syncthreads();
        if (tid < 64) {
            float v = (tid < 16) ? red[tid] : 0.0f;
            #pragma unroll
            for (int off = 8; off > 0; off >>= 1) v += __shfl_down(v, off, 64);
            if (tid == 0) red[16] = v;
        }
        __syncthreads();
        const float asum = red[16];
        const float inv = 1.0f / asum;
        for (int s = tid; s < S; s += nthr)
            alpha[s] = (anew[s] + coeff * leaky[s] * asum) * inv;
        logz += logf(asum);
        __syncthreads();
    }
    float fs = 0.0f;
    for (int s = tid; s < S; s += nthr) fs += alpha[s] * fin[s];
    #pragma unroll
    for (int off = 32; off > 0; off >>= 1) fs += __shfl_down(fs, off, 64);
    if ((tid & 63) == 0) red[tid >> 6] = fs;
    __syncthreads();
    if (tid < 64) {
        float v = (tid < 16) ? red[tid] : 0.0f;
        #pragma unroll
        for (int off = 8; off > 0; off >>= 1) v += __shfl_down(v, off, 64);
        if (tid == 0) part[blockIdx.x] = logz + logf(v);
    }
}

__global__ void combine_kernel(const float* __restrict__ part,
                               const int* __restrict__ lengths,
                               float* __restrict__ out)
{
    int tid = threadIdx.x;
    float v = 0.0f, l = 0.0f;
    if (tid < B_SZ) { v = part[tid] - part[B_SZ + tid]; l = (float)lengths[tid]; }
    #pragma unroll
    for (int off = 32; off > 0; off >>= 1) { v += __shfl_down(v, off, 64); l += __shfl_down(l, off, 64); }
    if (tid == 0) out[0] = v / l;
}

// ---------------------------------------------------------------------------
extern "C" void kernel_launch(void* const* d_in, const int* in_sizes, int n_in,
                              void* d_out, int out_size, void* d_ws, size_t ws_size,
                              hipStream_t stream)
{
    const float* x          = (const float*)d_in[0];
    const int*   lengths    = (const int*)  d_in[1];
    const int*   den_in_p   = (const int*)  d_in[2];
    const int*   den_out_p  = (const int*)  d_in[3];
    const int*   den_pdf_p  = (const int*)  d_in[4];
    const float* den_prob_p = (const float*)d_in[5];
    const float* den_leaky  = (const float*)d_in[6];
    const float* den_final  = (const float*)d_in[7];
    const int*   num_in_p   = (const int*)  d_in[8];
    const int*   num_out_p  = (const int*)  d_in[9];
    const int*   num_pdf_p  = (const int*)  d_in[10];
    const float* num_prob_p = (const float*)d_in[11];
    const float* num_leaky  = (const float*)d_in[12];
    const float* num_final  = (const float*)d_in[13];

    if (ws_size >= WS_BYTES) {
        char* ws = (char*)d_ws;
        hipLaunchKernelGGL(prep_init, dim3(1), dim3(256), 0, stream,
                           den_leaky, den_final, ws);
        hipLaunchKernelGGL(prep_hist, dim3((E_DEN + 255) / 256), dim3(256), 0, stream,
                           den_out_p, ws);
        hipLaunchKernelGGL(prep_scan, dim3(1), dim3(1024), 0, stream, ws);
        hipLaunchKernelGGL(prep_scatter, dim3((E_DEN + 255) / 256), dim3(256), 0, stream,
                           den_in_p, den_out_p, den_pdf_p, den_prob_p, ws);
        hipLaunchKernelGGL(prep_pack, dim3((EPAD + 255) / 256), dim3(256), 0, stream, ws);
        hipLaunchKernelGGL(chain_fwd2, dim3(2 * B_SZ), dim3(NTHR), 0, stream,
                           x, lengths, den_leaky, den_final,
                           num_in_p, num_out_p, num_pdf_p, num_prob_p,
                           num_leaky, num_final, ws);
        hipLaunchKernelGGL(combine2, dim3(1), dim3(64), 0, stream,
                           ws, lengths, (float*)d_out);
    } else {
        float* part = (float*)d_ws;
        hipLaunchKernelGGL(chain_fwd_kernel, dim3(2 * B_SZ), dim3(1024), 0, stream,
                           x, lengths,
                           den_in_p, den_out_p, den_pdf_p, den_prob_p, den_leaky, den_final,
                           num_in_p, num_out_p, num_pdf_p, num_prob_p, num_leaky, num_final,
                           part);
        hipLaunchKernelGGL(combine_kernel, dim3(1), dim3(64), 0, stream,
                           part, lengths, (float*)d_out);
    }
}